// Round 4
// baseline (205.277 us; speedup 1.0000x reference)
//
#include <hip/hip_runtime.h>

// B=4, C=128, H=4, D=32, N=2048.  All-fp16 MFMA pipeline with a canonical
// packed-fragment format: value block (16ch-tile rt, col n, quad q) lives at
// pk[(rt*2048+n)*16 + q*4 + j].  C-layout MFMA output == next B-frag (K=16),
// and pairs of quads give K=32 b128 frags.  No transposes, no LDS staging.
typedef __attribute__((ext_vector_type(4))) float v4f;
typedef __attribute__((ext_vector_type(8))) _Float16 half8;
typedef __attribute__((ext_vector_type(4))) _Float16 half4;
typedef __attribute__((ext_vector_type(2))) _Float16 half2t;

constexpr float C2 = 0.17677669529663687f * 1.44269504088896341f;  // rsqrt(32)*log2e

__device__ __forceinline__ half4 pk4(float a, float b, float c, float d) {
  half2t lo = __builtin_bit_cast(half2t, __builtin_amdgcn_cvt_pkrtz(a, b));
  half2t hi = __builtin_bit_cast(half2t, __builtin_amdgcn_cvt_pkrtz(c, d));
  return __builtin_shufflevector(lo, hi, 0, 1, 2, 3);
}

// ---------------------------------------------------------------------------
// prep: x1/x2 -> packed fp16 frags; weights -> fp16 row-major (wq,bq * C2);
// BN fold; mask -> additive exp2-domain bias.
// ---------------------------------------------------------------------------
__global__ __launch_bounds__(256) void prep(
    const float* __restrict__ x1, const float* __restrict__ x2,
    const float* __restrict__ wq, const float* __restrict__ bq,
    const float* __restrict__ wk, const float* __restrict__ wv,
    const float* __restrict__ wm, const float* __restrict__ wc1,
    const float* __restrict__ wc2, const float* __restrict__ gamma,
    const float* __restrict__ beta, const float* __restrict__ mean,
    const float* __restrict__ var, const unsigned char* __restrict__ mask,
    _Float16* __restrict__ x1pk, _Float16* __restrict__ x2pk,
    _Float16* __restrict__ wts, float* __restrict__ bqs,
    float* __restrict__ A1, float* __restrict__ B1,
    float* __restrict__ maskf) {
  const int id = blockIdx.x * 256 + threadIdx.x;
  if (id < 524288) {  // x packs: 2 x 262144 threads
    const int u = id & 262143;
    const float* __restrict__ src = (id < 262144) ? x1 : x2;
    _Float16* __restrict__ dst = (id < 262144) ? x1pk : x2pk;
    const int n = u & 2047, r = u >> 11;
    const int q = r & 3, ct = (r >> 2) & 7, b = r >> 5;
    const float* s = src + ((size_t)(b * 128 + ct * 16 + q * 4) * 2048 + n);
    const half4 v = pk4(s[0], s[2048], s[4096], s[6144]);
    *(half4*)(dst + ((size_t)(b * 8 + ct) * 2048 + n) * 16 + q * 4) = v;
  } else if (id < 565248) {  // weights: 40960 threads x 4 elems
    const int e = (id - 524288) * 4;
    const float* src;
    int base;
    float sc = 1.0f;
    if (e < 16384) { src = wq; base = 0; sc = C2; }
    else if (e < 32768) { src = wk; base = 16384; }
    else if (e < 49152) { src = wv; base = 32768; }
    else if (e < 65536) { src = wm; base = 49152; }
    else if (e < 131072) { src = wc1; base = 65536; }
    else { src = wc2; base = 131072; }
    const float4 t = *(const float4*)(src + (e - base));
    *(half4*)(wts + e) = pk4(t.x * sc, t.y * sc, t.z * sc, t.w * sc);
  } else if (id < 565312) {  // BN fold: 64 threads x 4
    const int i = (id - 565248) * 4;
#pragma unroll
    for (int j = 0; j < 4; ++j) {
      const int oi = i + j;
      const float sc = gamma[oi] * rsqrtf(var[oi] + 1e-5f);
      A1[oi] = sc;
      B1[oi] = beta[oi] - mean[oi] * sc;
    }
  } else if (id < 565344) {  // bq * C2: 32 threads x 4
    const int i = (id - 565312) * 4;
#pragma unroll
    for (int j = 0; j < 4; ++j) bqs[i + j] = bq[i + j] * C2;
  } else if (id < 567392) {  // maskf: 2048 threads x 4
    const int i = (id - 565344) * 4;
#pragma unroll
    for (int j = 0; j < 4; ++j)
      maskf[i + j] = mask[i + j] ? 0.0f : (-1.0e6f * C2);
  }
}

// ---------------------------------------------------------------------------
// qkv: Q,K natural GEMM -> packed [b][otile8][n][16]; V transposed GEMM
// (rows=keys) -> packed [bh][ktile128][d32][16] so PV A-frags are b64 loads.
// ---------------------------------------------------------------------------
__global__ __launch_bounds__(256) void qkv(
    const _Float16* __restrict__ x1pk, const _Float16* __restrict__ x2pk,
    const _Float16* __restrict__ wts, const float* __restrict__ bqs,
    const float* __restrict__ bk, const float* __restrict__ bv,
    _Float16* __restrict__ Qpk, _Float16* __restrict__ Kpk,
    _Float16* __restrict__ Vpk) {
  const int b = blockIdx.y;
  const int n0 = blockIdx.x * 64;
  const int tid = threadIdx.x, w = tid >> 6, lane = tid & 63;
  const int l = lane & 15, q = lane >> 4;
  const int n = n0 + w * 16 + l;
  const size_t xoff = ((size_t)(b * 8 + (q >> 1)) * 2048 + n) * 16 + (q & 1) * 8;

  half8 x1f[4], x2f[4];
#pragma unroll
  for (int kt = 0; kt < 4; ++kt) {
    x1f[kt] = *(const half8*)(x1pk + xoff + (size_t)kt * 2 * 2048 * 16);
    x2f[kt] = *(const half8*)(x2pk + xoff + (size_t)kt * 2 * 2048 * 16);
  }
  const _Float16* wq_h = wts;
  const _Float16* wk_h = wts + 16384;
  const _Float16* wv_h = wts + 32768;

#pragma unroll
  for (int mt = 0; mt < 8; ++mt) {  // Q
    v4f acc = *(const v4f*)(bqs + mt * 16 + q * 4);
#pragma unroll
    for (int kt = 0; kt < 4; ++kt) {
      const half8 wf = *(const half8*)(wq_h + (mt * 16 + l) * 128 + kt * 32 + q * 8);
      acc = __builtin_amdgcn_mfma_f32_16x16x32_f16(wf, x1f[kt], acc, 0, 0, 0);
    }
    *(half4*)(Qpk + ((size_t)(b * 8 + mt) * 2048 + n) * 16 + q * 4) =
        pk4(acc[0], acc[1], acc[2], acc[3]);
  }
#pragma unroll
  for (int mt = 0; mt < 8; ++mt) {  // K
    v4f acc = *(const v4f*)(bk + mt * 16 + q * 4);
#pragma unroll
    for (int kt = 0; kt < 4; ++kt) {
      const half8 wf = *(const half8*)(wk_h + (mt * 16 + l) * 128 + kt * 32 + q * 8);
      acc = __builtin_amdgcn_mfma_f32_16x16x32_f16(wf, x2f[kt], acc, 0, 0, 0);
    }
    *(half4*)(Kpk + ((size_t)(b * 8 + mt) * 2048 + n) * 16 + q * 4) =
        pk4(acc[0], acc[1], acc[2], acc[3]);
  }
  const int keytile = blockIdx.x * 4 + w;
#pragma unroll
  for (int ot = 0; ot < 8; ++ot) {  // V^T: rows = keys (this wave's 16 cols)
    const float bvv = bv[ot * 16 + l];
    v4f acc = {bvv, bvv, bvv, bvv};
#pragma unroll
    for (int kt = 0; kt < 4; ++kt) {
      const half8 wf = *(const half8*)(wv_h + (ot * 16 + l) * 128 + kt * 32 + q * 8);
      acc = __builtin_amdgcn_mfma_f32_16x16x32_f16(x2f[kt], wf, acc, 0, 0, 0);
    }
    *(half4*)(Vpk + (((size_t)(b * 4 + (ot >> 1)) * 128 + keytile) * 32 +
                     (ot & 1) * 16 + l) * 16 + q * 4) =
        pk4(acc[0], acc[1], acc[2], acc[3]);
  }
}

// ---------------------------------------------------------------------------
// attn: QK 16x16x32 (Sᵀ, mask bias in C); exp2 in regs; P regs ARE the PV
// B-frags (16x16x16, V as A).  No LDS, no shuffles in loop.  2-way key split;
// unnormalized fp16 O parts + fp32 lsum parts merged in post.
// ---------------------------------------------------------------------------
__global__ __launch_bounds__(256) void attn(
    const _Float16* __restrict__ Qpk, const _Float16* __restrict__ Kpk,
    const _Float16* __restrict__ Vpk, const float* __restrict__ maskf,
    _Float16* __restrict__ Opk, float* __restrict__ lsump) {
  const int bh = blockIdx.y, b = bh >> 2, h = bh & 3;
  const int n0 = blockIdx.x * 64;
  const int part = blockIdx.z;
  const int tid = threadIdx.x, w = tid >> 6, lane = tid & 63;
  const int l = lane & 15, q = lane >> 4;
  const int n = n0 + w * 16 + l;

  const half8 qf = *(const half8*)(
      Qpk + ((size_t)(b * 8 + h * 2 + (q >> 1)) * 2048 + n) * 16 + (q & 1) * 8);
  const _Float16* __restrict__ Kb =
      Kpk + ((size_t)(b * 8 + h * 2 + (q >> 1)) * 2048) * 16 + (q & 1) * 8;
  const _Float16* __restrict__ Vb =
      Vpk + ((size_t)(b * 4 + h) * 128) * 512 + (size_t)l * 16 + q * 4;
  const float* __restrict__ mf = maskf + b * 2048;

  v4f oacc[2] = {{0.f, 0.f, 0.f, 0.f}, {0.f, 0.f, 0.f, 0.f}};
  float lsum = 0.f;

  const int mbeg = part * 1024;
  for (int m0 = mbeg; m0 < mbeg + 1024; m0 += 64) {
    v4f s[4];
#pragma unroll
    for (int mt = 0; mt < 4; ++mt) {
      const half8 kf = *(const half8*)(Kb + (size_t)(m0 + mt * 16 + l) * 16);
      const v4f biasv = *(const v4f*)(mf + m0 + mt * 16 + q * 4);
      s[mt] = __builtin_amdgcn_mfma_f32_16x16x32_f16(kf, qf, biasv, 0, 0, 0);
    }
    half4 pB[4];
#pragma unroll
    for (int mt = 0; mt < 4; ++mt) {
      const float p0 = exp2f(s[mt][0]), p1 = exp2f(s[mt][1]);
      const float p2 = exp2f(s[mt][2]), p3 = exp2f(s[mt][3]);
      lsum += (p0 + p1) + (p2 + p3);
      pB[mt] = pk4(p0, p1, p2, p3);
    }
#pragma unroll
    for (int mt = 0; mt < 4; ++mt) {
      const size_t vbase = (size_t)((m0 >> 4) + mt) * 512;
#pragma unroll
      for (int df = 0; df < 2; ++df) {
        const half4 vf = *(const half4*)(Vb + vbase + df * 256);
        oacc[df] =
            __builtin_amdgcn_mfma_f32_16x16x16f16(vf, pB[mt], oacc[df], 0, 0, 0);
      }
    }
  }
  lsum += __shfl_xor(lsum, 16);
  lsum += __shfl_xor(lsum, 32);
  if (q == 0) lsump[part * 32768 + bh * 2048 + n] = lsum;
#pragma unroll
  for (int df = 0; df < 2; ++df)
    *(half4*)(Opk + (size_t)part * 1048576 +
              ((size_t)(b * 8 + h * 2 + df) * 2048 + n) * 16 + q * 4) =
        pk4(oacc[df][0], oacc[df][1], oacc[df][2], oacc[df][3]);
}

// ---------------------------------------------------------------------------
// post: merge+normalize O into B-frags, then wm/wc1(BN,ReLU)/wc2 chain fully
// in registers (C-layout == next B-frag identity), fp32 residual from x1.
// ---------------------------------------------------------------------------
__global__ __launch_bounds__(256) void post(
    const float* __restrict__ x1, const _Float16* __restrict__ Opk,
    const float* __restrict__ lsump, const _Float16* __restrict__ wts,
    const float* __restrict__ bm, const float* __restrict__ bc1,
    const float* __restrict__ A1, const float* __restrict__ B1,
    const float* __restrict__ bc2, float* __restrict__ out) {
  const int b = blockIdx.y;
  const int n0 = blockIdx.x * 64;
  const int tid = threadIdx.x, w = tid >> 6, lane = tid & 63;
  const int l = lane & 15, q = lane >> 4;
  const int n = n0 + w * 16 + l;
  const _Float16* wm_h = wts + 49152;
  const _Float16* wc1_h = wts + 65536;
  const _Float16* wc2_h = wts + 131072;

  __shared__ float rl[256];
  {
    const int hh = tid >> 6, nn = tid & 63;
    const size_t idx = (size_t)(b * 4 + hh) * 2048 + n0 + nn;
    rl[tid] = 1.0f / (lsump[idx] + lsump[32768 + idx]);
  }
  __syncthreads();

  float xr[8][4];
  half4 catf[16];
#pragma unroll
  for (int kt = 0; kt < 8; ++kt) {
#pragma unroll
    for (int j = 0; j < 4; ++j)
      xr[kt][j] = x1[(size_t)(b * 128 + kt * 16 + q * 4 + j) * 2048 + n];
    catf[kt] = pk4(xr[kt][0], xr[kt][1], xr[kt][2], xr[kt][3]);
  }
  half4 of[8];
#pragma unroll
  for (int kt = 0; kt < 8; ++kt) {
    const size_t oa = ((size_t)(b * 8 + kt) * 2048 + n) * 16 + q * 4;
    const half4 a = *(const half4*)(Opk + oa);
    const half4 c = *(const half4*)(Opk + 1048576 + oa);
    const _Float16 rh = (_Float16)rl[(kt >> 1) * 64 + w * 16 + l];
    const half4 rl4 = {rh, rh, rh, rh};
    of[kt] = (a + c) * rl4;
  }
  // phase A: t = wm @ O + bm  -> catf[8..15]
#pragma unroll
  for (int mt = 0; mt < 8; ++mt) {
    v4f acc = *(const v4f*)(bm + mt * 16 + q * 4);
#pragma unroll
    for (int kt = 0; kt < 8; ++kt) {
      const half4 wf = *(const half4*)(wm_h + (mt * 16 + l) * 128 + kt * 16 + q * 4);
      acc = __builtin_amdgcn_mfma_f32_16x16x16f16(wf, of[kt], acc, 0, 0, 0);
    }
    catf[8 + mt] = pk4(acc[0], acc[1], acc[2], acc[3]);
  }
  // phase B: h1 = relu(BN(wc1 @ cat + bc1))
  half4 hf[16];
#pragma unroll
  for (int mt = 0; mt < 16; ++mt) {
    v4f acc = *(const v4f*)(bc1 + mt * 16 + q * 4);
#pragma unroll
    for (int kt = 0; kt < 16; ++kt) {
      const half4 wf = *(const half4*)(wc1_h + (mt * 16 + l) * 256 + kt * 16 + q * 4);
      acc = __builtin_amdgcn_mfma_f32_16x16x16f16(wf, catf[kt], acc, 0, 0, 0);
    }
    const v4f a1 = *(const v4f*)(A1 + mt * 16 + q * 4);
    const v4f b1 = *(const v4f*)(B1 + mt * 16 + q * 4);
    float h0 = fmaxf(acc[0] * a1[0] + b1[0], 0.f);
    float h1 = fmaxf(acc[1] * a1[1] + b1[1], 0.f);
    float h2 = fmaxf(acc[2] * a1[2] + b1[2], 0.f);
    float h3 = fmaxf(acc[3] * a1[3] + b1[3], 0.f);
    hf[mt] = pk4(h0, h1, h2, h3);
  }
  // phase C: out = x1 + wc2 @ h1 + bc2
#pragma unroll
  for (int mt = 0; mt < 8; ++mt) {
    v4f acc = *(const v4f*)(bc2 + mt * 16 + q * 4);
#pragma unroll
    for (int kt = 0; kt < 16; ++kt) {
      const half4 wf = *(const half4*)(wc2_h + (mt * 16 + l) * 256 + kt * 16 + q * 4);
      acc = __builtin_amdgcn_mfma_f32_16x16x16f16(wf, hf[kt], acc, 0, 0, 0);
    }
#pragma unroll
    for (int r = 0; r < 4; ++r)
      out[(size_t)(b * 128 + mt * 16 + q * 4 + r) * 2048 + n] =
          acc[r] + xr[mt][r];
  }
}

// ---------------------------------------------------------------------------
extern "C" void kernel_launch(void* const* d_in, const int* in_sizes, int n_in,
                              void* d_out, int out_size, void* d_ws,
                              size_t ws_size, hipStream_t stream) {
  const float* x1 = (const float*)d_in[0];
  const float* x2 = (const float*)d_in[1];
  const unsigned char* kv_mask = (const unsigned char*)d_in[2];
  const float* wq = (const float*)d_in[3];
  const float* bq = (const float*)d_in[4];
  const float* wk = (const float*)d_in[5];
  const float* bk = (const float*)d_in[6];
  const float* wv = (const float*)d_in[7];
  const float* bv = (const float*)d_in[8];
  const float* wm = (const float*)d_in[9];
  const float* bm = (const float*)d_in[10];
  const float* wc1 = (const float*)d_in[11];
  const float* bc1 = (const float*)d_in[12];
  const float* bn_gamma = (const float*)d_in[13];
  const float* bn_beta = (const float*)d_in[14];
  const float* bn_mean = (const float*)d_in[15];
  const float* bn_var = (const float*)d_in[16];
  const float* wc2 = (const float*)d_in[17];
  const float* bc2 = (const float*)d_in[18];
  float* out = (float*)d_out;

  // ws layout (bytes): x1pk 2M | x2pk 2M | Qpk 2M | Kpk 2M | Vpk 2M |
  //                    Opk 4M | wts 320K | lsump 256K | maskf 32K | bqs/A1/B1
  char* p = (char*)d_ws;
  _Float16* x1pk = (_Float16*)p;
  _Float16* x2pk = (_Float16*)(p + (size_t)2 * 1024 * 1024);
  _Float16* Qpk = (_Float16*)(p + (size_t)4 * 1024 * 1024);
  _Float16* Kpk = (_Float16*)(p + (size_t)6 * 1024 * 1024);
  _Float16* Vpk = (_Float16*)(p + (size_t)8 * 1024 * 1024);
  _Float16* Opk = (_Float16*)(p + (size_t)10 * 1024 * 1024);
  _Float16* wts = (_Float16*)(p + (size_t)14 * 1024 * 1024);
  float* lsump = (float*)(p + (size_t)14 * 1024 * 1024 + 512 * 1024);
  float* maskf = lsump + 65536;
  float* bqs = maskf + 8192;
  float* A1 = bqs + 128;
  float* B1 = A1 + 256;

  prep<<<2217, 256, 0, stream>>>(x1, x2, wq, bq, wk, wv, wm, wc1, wc2,
                                 bn_gamma, bn_beta, bn_mean, bn_var, kv_mask,
                                 x1pk, x2pk, wts, bqs, A1, B1, maskf);
  qkv<<<dim3(32, 4), 256, 0, stream>>>(x1pk, x2pk, wts, bqs, bk, bv, Qpk, Kpk,
                                       Vpk);
  attn<<<dim3(32, 16, 2), 256, 0, stream>>>(Qpk, Kpk, Vpk, maskf, Opk, lsump);
  post<<<dim3(32, 4), 256, 0, stream>>>(x1, Opk, lsump, wts, bm, bc1, A1, B1,
                                        bc2, out);
}

// Round 5
// 168.499 us; speedup vs baseline: 1.2183x; 1.2183x over previous
//
#include <hip/hip_runtime.h>

// B=4, C=128, H=4, D=32, N=2048.  All-fp16 MFMA pipeline with a canonical
// packed-fragment format: value block (16ch-tile rt, col n, quad q) lives at
// pk[(rt*2048+n)*16 + q*4 + j].  C-layout MFMA output == next B-frag (K=16),
// pairs of quads give K=32 b128 frags.  R4: 8-wave blocks per 16-col group in
// qkv/post (tile-split across waves, LDS frag exchange) to fix 5% occupancy.
typedef __attribute__((ext_vector_type(4))) float v4f;
typedef __attribute__((ext_vector_type(8))) _Float16 half8;
typedef __attribute__((ext_vector_type(4))) _Float16 half4;
typedef __attribute__((ext_vector_type(2))) _Float16 half2t;

constexpr float C2 = 0.17677669529663687f * 1.44269504088896341f;  // rsqrt(32)*log2e

__device__ __forceinline__ half4 pk4(float a, float b, float c, float d) {
  half2t lo = __builtin_bit_cast(half2t, __builtin_amdgcn_cvt_pkrtz(a, b));
  half2t hi = __builtin_bit_cast(half2t, __builtin_amdgcn_cvt_pkrtz(c, d));
  return __builtin_shufflevector(lo, hi, 0, 1, 2, 3);
}

// ---------------------------------------------------------------------------
// prep: x1/x2 -> packed fp16 frags; weights -> fp16 row-major (wq,bq * C2);
// BN fold; mask -> additive exp2-domain bias.
// ---------------------------------------------------------------------------
__global__ __launch_bounds__(256) void prep(
    const float* __restrict__ x1, const float* __restrict__ x2,
    const float* __restrict__ wq, const float* __restrict__ bq,
    const float* __restrict__ wk, const float* __restrict__ wv,
    const float* __restrict__ wm, const float* __restrict__ wc1,
    const float* __restrict__ wc2, const float* __restrict__ gamma,
    const float* __restrict__ beta, const float* __restrict__ mean,
    const float* __restrict__ var, const unsigned char* __restrict__ mask,
    _Float16* __restrict__ x1pk, _Float16* __restrict__ x2pk,
    _Float16* __restrict__ wts, float* __restrict__ bqs,
    float* __restrict__ A1, float* __restrict__ B1,
    float* __restrict__ maskf) {
  const int id = blockIdx.x * 256 + threadIdx.x;
  if (id < 524288) {  // x packs
    const int u = id & 262143;
    const float* __restrict__ src = (id < 262144) ? x1 : x2;
    _Float16* __restrict__ dst = (id < 262144) ? x1pk : x2pk;
    const int n = u & 2047, r = u >> 11;
    const int q = r & 3, ct = (r >> 2) & 7, b = r >> 5;
    const float* s = src + ((size_t)(b * 128 + ct * 16 + q * 4) * 2048 + n);
    const half4 v = pk4(s[0], s[2048], s[4096], s[6144]);
    *(half4*)(dst + ((size_t)(b * 8 + ct) * 2048 + n) * 16 + q * 4) = v;
  } else if (id < 565248) {  // weights
    const int e = (id - 524288) * 4;
    const float* src;
    int base;
    float sc = 1.0f;
    if (e < 16384) { src = wq; base = 0; sc = C2; }
    else if (e < 32768) { src = wk; base = 16384; }
    else if (e < 49152) { src = wv; base = 32768; }
    else if (e < 65536) { src = wm; base = 49152; }
    else if (e < 131072) { src = wc1; base = 65536; }
    else { src = wc2; base = 131072; }
    const float4 t = *(const float4*)(src + (e - base));
    *(half4*)(wts + e) = pk4(t.x * sc, t.y * sc, t.z * sc, t.w * sc);
  } else if (id < 565312) {  // BN fold
    const int i = (id - 565248) * 4;
#pragma unroll
    for (int j = 0; j < 4; ++j) {
      const int oi = i + j;
      const float sc = gamma[oi] * rsqrtf(var[oi] + 1e-5f);
      A1[oi] = sc;
      B1[oi] = beta[oi] - mean[oi] * sc;
    }
  } else if (id < 565344) {  // bq * C2
    const int i = (id - 565312) * 4;
#pragma unroll
    for (int j = 0; j < 4; ++j) bqs[i + j] = bq[i + j] * C2;
  } else if (id < 567392) {  // maskf
    const int i = (id - 565344) * 4;
#pragma unroll
    for (int j = 0; j < 4; ++j)
      maskf[i + j] = mask[i + j] ? 0.0f : (-1.0e6f * C2);
  }
}

// ---------------------------------------------------------------------------
// qkv: 8 waves per 16-col group; wave w owns 3 of 24 output tiles
// (Q0..7,K0..7,V0..7).  No barriers, no LDS.  grid (128,4).
// ---------------------------------------------------------------------------
__global__ __launch_bounds__(512) void qkv(
    const _Float16* __restrict__ x1pk, const _Float16* __restrict__ x2pk,
    const _Float16* __restrict__ wts, const float* __restrict__ bqs,
    const float* __restrict__ bk, const float* __restrict__ bv,
    _Float16* __restrict__ Qpk, _Float16* __restrict__ Kpk,
    _Float16* __restrict__ Vpk) {
  const int b = blockIdx.y;
  const int bx = blockIdx.x;  // 16-col group == keytile for V
  const int tid = threadIdx.x, w = tid >> 6, lane = tid & 63;
  const int l = lane & 15, q = lane >> 4;
  const int n = bx * 16 + l;
  const size_t xoff = ((size_t)(b * 8 + (q >> 1)) * 2048 + n) * 16 + (q & 1) * 8;

  half8 x1f[4], x2f[4];
#pragma unroll
  for (int kt = 0; kt < 4; ++kt) {
    x1f[kt] = *(const half8*)(x1pk + xoff + (size_t)kt * 2 * 2048 * 16);
    x2f[kt] = *(const half8*)(x2pk + xoff + (size_t)kt * 2 * 2048 * 16);
  }
  const _Float16* wq_h = wts;
  const _Float16* wk_h = wts + 16384;
  const _Float16* wv_h = wts + 32768;

#pragma unroll
  for (int i = 0; i < 3; ++i) {
    const int t = w * 3 + i;  // wave-uniform
    if (t < 8) {              // Q tile mt=t
      const int mt = t;
      v4f acc = *(const v4f*)(bqs + mt * 16 + q * 4);
#pragma unroll
      for (int kt = 0; kt < 4; ++kt) {
        const half8 wf =
            *(const half8*)(wq_h + (mt * 16 + l) * 128 + kt * 32 + q * 8);
        acc = __builtin_amdgcn_mfma_f32_16x16x32_f16(wf, x1f[kt], acc, 0, 0, 0);
      }
      *(half4*)(Qpk + ((size_t)(b * 8 + mt) * 2048 + n) * 16 + q * 4) =
          pk4(acc[0], acc[1], acc[2], acc[3]);
    } else if (t < 16) {  // K tile mt=t-8
      const int mt = t - 8;
      v4f acc = *(const v4f*)(bk + mt * 16 + q * 4);
#pragma unroll
      for (int kt = 0; kt < 4; ++kt) {
        const half8 wf =
            *(const half8*)(wk_h + (mt * 16 + l) * 128 + kt * 32 + q * 8);
        acc = __builtin_amdgcn_mfma_f32_16x16x32_f16(wf, x2f[kt], acc, 0, 0, 0);
      }
      *(half4*)(Kpk + ((size_t)(b * 8 + mt) * 2048 + n) * 16 + q * 4) =
          pk4(acc[0], acc[1], acc[2], acc[3]);
    } else {  // V^T tile ot=t-16 (rows = keys)
      const int ot = t - 16;
      const float bvv = bv[ot * 16 + l];
      v4f acc = {bvv, bvv, bvv, bvv};
#pragma unroll
      for (int kt = 0; kt < 4; ++kt) {
        const half8 wf =
            *(const half8*)(wv_h + (ot * 16 + l) * 128 + kt * 32 + q * 8);
        acc = __builtin_amdgcn_mfma_f32_16x16x32_f16(x2f[kt], wf, acc, 0, 0, 0);
      }
      *(half4*)(Vpk + (((size_t)(b * 4 + (ot >> 1)) * 128 + bx) * 32 +
                       (ot & 1) * 16 + l) * 16 + q * 4) =
          pk4(acc[0], acc[1], acc[2], acc[3]);
    }
  }
}

// ---------------------------------------------------------------------------
// attn: QK 16x16x32 (Sᵀ, mask bias in C); exp2 in regs; P regs ARE the PV
// B-frags (16x16x16, V as A).  No LDS, no shuffles in loop.  2-way key split.
// ---------------------------------------------------------------------------
__global__ __launch_bounds__(256) void attn(
    const _Float16* __restrict__ Qpk, const _Float16* __restrict__ Kpk,
    const _Float16* __restrict__ Vpk, const float* __restrict__ maskf,
    _Float16* __restrict__ Opk, float* __restrict__ lsump) {
  const int bh = blockIdx.y, b = bh >> 2, h = bh & 3;
  const int n0 = blockIdx.x * 64;
  const int part = blockIdx.z;
  const int tid = threadIdx.x, w = tid >> 6, lane = tid & 63;
  const int l = lane & 15, q = lane >> 4;
  const int n = n0 + w * 16 + l;

  const half8 qf = *(const half8*)(
      Qpk + ((size_t)(b * 8 + h * 2 + (q >> 1)) * 2048 + n) * 16 + (q & 1) * 8);
  const _Float16* __restrict__ Kb =
      Kpk + ((size_t)(b * 8 + h * 2 + (q >> 1)) * 2048) * 16 + (q & 1) * 8;
  const _Float16* __restrict__ Vb =
      Vpk + ((size_t)(b * 4 + h) * 128) * 512 + (size_t)l * 16 + q * 4;
  const float* __restrict__ mf = maskf + b * 2048;

  v4f oacc[2] = {{0.f, 0.f, 0.f, 0.f}, {0.f, 0.f, 0.f, 0.f}};
  float lsum = 0.f;

  const int mbeg = part * 1024;
  for (int m0 = mbeg; m0 < mbeg + 1024; m0 += 64) {
    v4f s[4];
#pragma unroll
    for (int mt = 0; mt < 4; ++mt) {
      const half8 kf = *(const half8*)(Kb + (size_t)(m0 + mt * 16 + l) * 16);
      const v4f biasv = *(const v4f*)(mf + m0 + mt * 16 + q * 4);
      s[mt] = __builtin_amdgcn_mfma_f32_16x16x32_f16(kf, qf, biasv, 0, 0, 0);
    }
    half4 pB[4];
#pragma unroll
    for (int mt = 0; mt < 4; ++mt) {
      const float p0 = exp2f(s[mt][0]), p1 = exp2f(s[mt][1]);
      const float p2 = exp2f(s[mt][2]), p3 = exp2f(s[mt][3]);
      lsum += (p0 + p1) + (p2 + p3);
      pB[mt] = pk4(p0, p1, p2, p3);
    }
#pragma unroll
    for (int mt = 0; mt < 4; ++mt) {
      const size_t vbase = (size_t)((m0 >> 4) + mt) * 512;
#pragma unroll
      for (int df = 0; df < 2; ++df) {
        const half4 vf = *(const half4*)(Vb + vbase + df * 256);
        oacc[df] =
            __builtin_amdgcn_mfma_f32_16x16x16f16(vf, pB[mt], oacc[df], 0, 0, 0);
      }
    }
  }
  lsum += __shfl_xor(lsum, 16);
  lsum += __shfl_xor(lsum, 32);
  if (q == 0) lsump[part * 32768 + bh * 2048 + n] = lsum;
#pragma unroll
  for (int df = 0; df < 2; ++df)
    *(half4*)(Opk + (size_t)part * 1048576 +
              ((size_t)(b * 8 + h * 2 + df) * 2048 + n) * 16 + q * 4) =
        pk4(oacc[df][0], oacc[df][1], oacc[df][2], oacc[df][3]);
}

// ---------------------------------------------------------------------------
// post: 8 waves per 16-col group; tile-split phases with LDS frag exchange.
// A: wave w -> cat tile 8+w.  B: wave w -> h1 tiles 2w,2w+1.  C: wave w ->
// out tile w.  grid (128,4).
// ---------------------------------------------------------------------------
__global__ __launch_bounds__(512) void post(
    const float* __restrict__ x1, const _Float16* __restrict__ Opk,
    const float* __restrict__ lsump, const _Float16* __restrict__ wts,
    const float* __restrict__ bm, const float* __restrict__ bc1,
    const float* __restrict__ A1, const float* __restrict__ B1,
    const float* __restrict__ bc2, float* __restrict__ out) {
  const int b = blockIdx.y;
  const int n0 = blockIdx.x * 16;
  const int tid = threadIdx.x, w = tid >> 6, lane = tid & 63;
  const int l = lane & 15, q = lane >> 4;
  const int n = n0 + l;
  const _Float16* wm_h = wts + 49152;
  const _Float16* wc1_h = wts + 65536;
  const _Float16* wc2_h = wts + 131072;

  __shared__ _Float16 exA[8 * 256];   // phase-A outputs (cat tiles 8..15)
  __shared__ _Float16 exB[16 * 256];  // phase-B outputs (h1 tiles 0..15)

  float rlh[4];
#pragma unroll
  for (int hh = 0; hh < 4; ++hh) {
    const size_t idx = (size_t)(b * 4 + hh) * 2048 + n;
    rlh[hh] = 1.0f / (lsump[idx] + lsump[32768 + idx]);
  }
  half4 of[8];
#pragma unroll
  for (int kt = 0; kt < 8; ++kt) {
    const size_t oa = ((size_t)(b * 8 + kt) * 2048 + n) * 16 + q * 4;
    const half4 a = *(const half4*)(Opk + oa);
    const half4 c = *(const half4*)(Opk + 1048576 + oa);
    const _Float16 rh = (_Float16)rlh[kt >> 1];
    const half4 rl4 = {rh, rh, rh, rh};
    of[kt] = (a + c) * rl4;
  }
  half4 catf[16];
  float xr[4];
#pragma unroll
  for (int kt = 0; kt < 8; ++kt) {
    float v0 = x1[(size_t)(b * 128 + kt * 16 + q * 4 + 0) * 2048 + n];
    float v1 = x1[(size_t)(b * 128 + kt * 16 + q * 4 + 1) * 2048 + n];
    float v2 = x1[(size_t)(b * 128 + kt * 16 + q * 4 + 2) * 2048 + n];
    float v3 = x1[(size_t)(b * 128 + kt * 16 + q * 4 + 3) * 2048 + n];
    if (kt == w) { xr[0] = v0; xr[1] = v1; xr[2] = v2; xr[3] = v3; }
    catf[kt] = pk4(v0, v1, v2, v3);
  }
  {  // phase A: wave w computes cat tile 8+w = wm@O + bm (tile w of wm)
    v4f acc = *(const v4f*)(bm + w * 16 + q * 4);
#pragma unroll
    for (int kt = 0; kt < 8; ++kt) {
      const half4 wf =
          *(const half4*)(wm_h + (w * 16 + l) * 128 + kt * 16 + q * 4);
      acc = __builtin_amdgcn_mfma_f32_16x16x16f16(wf, of[kt], acc, 0, 0, 0);
    }
    *(half4*)&exA[w * 256 + l * 16 + q * 4] = pk4(acc[0], acc[1], acc[2], acc[3]);
  }
  __syncthreads();
#pragma unroll
  for (int f = 0; f < 8; ++f)
    catf[8 + f] = *(const half4*)&exA[f * 256 + l * 16 + q * 4];
  // phase B: wave w computes h1 tiles 2w, 2w+1
#pragma unroll
  for (int i = 0; i < 2; ++i) {
    const int mt = w * 2 + i;
    v4f acc = *(const v4f*)(bc1 + mt * 16 + q * 4);
#pragma unroll
    for (int kt = 0; kt < 16; ++kt) {
      const half4 wf =
          *(const half4*)(wc1_h + (mt * 16 + l) * 256 + kt * 16 + q * 4);
      acc = __builtin_amdgcn_mfma_f32_16x16x16f16(wf, catf[kt], acc, 0, 0, 0);
    }
    const v4f a1 = *(const v4f*)(A1 + mt * 16 + q * 4);
    const v4f b1 = *(const v4f*)(B1 + mt * 16 + q * 4);
    const float h0 = fmaxf(acc[0] * a1[0] + b1[0], 0.f);
    const float h1 = fmaxf(acc[1] * a1[1] + b1[1], 0.f);
    const float h2 = fmaxf(acc[2] * a1[2] + b1[2], 0.f);
    const float h3 = fmaxf(acc[3] * a1[3] + b1[3], 0.f);
    *(half4*)&exB[mt * 256 + l * 16 + q * 4] = pk4(h0, h1, h2, h3);
  }
  __syncthreads();
  {  // phase C: wave w computes out tile w = x1 + wc2@h1 + bc2
    v4f acc = *(const v4f*)(bc2 + w * 16 + q * 4);
#pragma unroll
    for (int kt = 0; kt < 16; ++kt) {
      const half4 hfv = *(const half4*)&exB[kt * 256 + l * 16 + q * 4];
      const half4 wf =
          *(const half4*)(wc2_h + (w * 16 + l) * 256 + kt * 16 + q * 4);
      acc = __builtin_amdgcn_mfma_f32_16x16x16f16(wf, hfv, acc, 0, 0, 0);
    }
#pragma unroll
    for (int r = 0; r < 4; ++r)
      out[(size_t)(b * 128 + w * 16 + q * 4 + r) * 2048 + n] = acc[r] + xr[r];
  }
}

// ---------------------------------------------------------------------------
extern "C" void kernel_launch(void* const* d_in, const int* in_sizes, int n_in,
                              void* d_out, int out_size, void* d_ws,
                              size_t ws_size, hipStream_t stream) {
  const float* x1 = (const float*)d_in[0];
  const float* x2 = (const float*)d_in[1];
  const unsigned char* kv_mask = (const unsigned char*)d_in[2];
  const float* wq = (const float*)d_in[3];
  const float* bq = (const float*)d_in[4];
  const float* wk = (const float*)d_in[5];
  const float* bk = (const float*)d_in[6];
  const float* wv = (const float*)d_in[7];
  const float* bv = (const float*)d_in[8];
  const float* wm = (const float*)d_in[9];
  const float* bm = (const float*)d_in[10];
  const float* wc1 = (const float*)d_in[11];
  const float* bc1 = (const float*)d_in[12];
  const float* bn_gamma = (const float*)d_in[13];
  const float* bn_beta = (const float*)d_in[14];
  const float* bn_mean = (const float*)d_in[15];
  const float* bn_var = (const float*)d_in[16];
  const float* wc2 = (const float*)d_in[17];
  const float* bc2 = (const float*)d_in[18];
  float* out = (float*)d_out;

  char* p = (char*)d_ws;
  _Float16* x1pk = (_Float16*)p;
  _Float16* x2pk = (_Float16*)(p + (size_t)2 * 1024 * 1024);
  _Float16* Qpk = (_Float16*)(p + (size_t)4 * 1024 * 1024);
  _Float16* Kpk = (_Float16*)(p + (size_t)6 * 1024 * 1024);
  _Float16* Vpk = (_Float16*)(p + (size_t)8 * 1024 * 1024);
  _Float16* Opk = (_Float16*)(p + (size_t)10 * 1024 * 1024);
  _Float16* wts = (_Float16*)(p + (size_t)14 * 1024 * 1024);
  float* lsump = (float*)(p + (size_t)14 * 1024 * 1024 + 512 * 1024);
  float* maskf = lsump + 65536;
  float* bqs = maskf + 8192;
  float* A1 = bqs + 128;
  float* B1 = A1 + 256;

  prep<<<2217, 256, 0, stream>>>(x1, x2, wq, bq, wk, wv, wm, wc1, wc2,
                                 bn_gamma, bn_beta, bn_mean, bn_var, kv_mask,
                                 x1pk, x2pk, wts, bqs, A1, B1, maskf);
  qkv<<<dim3(128, 4), 512, 0, stream>>>(x1pk, x2pk, wts, bqs, bk, bv, Qpk, Kpk,
                                        Vpk);
  attn<<<dim3(32, 16, 2), 256, 0, stream>>>(Qpk, Kpk, Vpk, maskf, Opk, lsump);
  post<<<dim3(128, 4), 512, 0, stream>>>(x1, Opk, lsump, wts, bm, bc1, A1, B1,
                                         bc2, out);
}